// Round 1
// baseline (778.156 us; speedup 1.0000x reference)
//
#include <hip/hip_runtime.h>

// CRF Viterbi forward decode.
// potentials: [1024, 512, 48] f32, transition: [48, 48] f32.
// out = backpointers [1024, 511, 48] (written as float values) ++ scores [1024, 48] f32.
//
// Layout: 1 block = 1 wave (48 active lanes) = 1 batch. lane = destination tag j.
// trans column j lives in 48 VGPRs (t-invariant). State ping-pongs through LDS
// (wave-uniform broadcast reads). 4 independent argmax chains over contiguous
// i-ranges preserve first-occurrence tie-breaking and give ILP at 1 wave/SIMD.

constexpr int B_ = 1024;
constexpr int T_ = 512;
constexpr int K_ = 48;

#define CAND(mm, xx, val, ii) do { float _s = (val); if (_s > (mm)) { (mm) = _s; (xx) = (ii); } } while (0)

__global__ __launch_bounds__(64) void crf_viterbi_kernel(
    const float* __restrict__ pot,
    const float* __restrict__ trans,
    float* __restrict__ out)
{
    const int b = blockIdx.x;
    const int j = threadIdx.x;  // 0..47

    __shared__ float4 stv[2][K_ / 4];  // ping-pong state buffers

    // Transition column j -> registers (reused 511 times).
    float tcol[K_];
    #pragma unroll
    for (int i = 0; i < K_; ++i) tcol[i] = trans[i * K_ + j];

    const float* pp   = pot + (size_t)b * T_ * K_ + j;
    float* bpout      = out + (size_t)b * (T_ - 1) * K_ + j;
    float* scout      = out + (size_t)B_ * (T_ - 1) * K_ + (size_t)b * K_ + j;

    // t = 0: init state.
    float myst = pp[0];
    ((float*)&stv[0][0])[j] = myst;
    __syncthreads();

    // Prefetch potentials for t = 1..4.
    float pbuf[4];
    #pragma unroll
    for (int u = 0; u < 4; ++u) pbuf[u] = pp[(1 + u) * K_];

    for (int t0 = 1; t0 < T_; t0 += 4) {
        float pc[4];
        #pragma unroll
        for (int u = 0; u < 4; ++u) pc[u] = pbuf[u];

        // Prefetch next 4 steps (clamped; duplicate loads are harmless).
        #pragma unroll
        for (int u = 0; u < 4; ++u) {
            int tn = t0 + 4 + u;
            if (tn > T_ - 1) tn = T_ - 1;
            pbuf[u] = pp[tn * K_];
        }

        #pragma unroll
        for (int u = 0; u < 4; ++u) {
            const int t = t0 + u;
            if (t < T_) {               // uniform guard (only fails on last chunk)
                const int rb = u & 1;   // compile-time after unroll: 4 flips/chunk

                float m[4];
                int   x[4];
                // Chain n covers i in [12n, 12n+12): contiguous + ascending, so
                // strict '>' gives first-occurrence argmax within the chain.
                #pragma unroll
                for (int n = 0; n < 4; ++n) {
                    float4 v = stv[rb][3 * n];
                    m[n] = v.x + tcol[12 * n];
                    x[n] = 12 * n;
                    CAND(m[n], x[n], v.y + tcol[12 * n + 1], 12 * n + 1);
                    CAND(m[n], x[n], v.z + tcol[12 * n + 2], 12 * n + 2);
                    CAND(m[n], x[n], v.w + tcol[12 * n + 3], 12 * n + 3);
                    #pragma unroll
                    for (int c = 1; c < 3; ++c) {
                        float4 w = stv[rb][3 * n + c];
                        const int base = 12 * n + 4 * c;
                        CAND(m[n], x[n], w.x + tcol[base + 0], base + 0);
                        CAND(m[n], x[n], w.y + tcol[base + 1], base + 1);
                        CAND(m[n], x[n], w.z + tcol[base + 2], base + 2);
                        CAND(m[n], x[n], w.w + tcol[base + 3], base + 3);
                    }
                }
                // Tree merge, left wins ties -> global first-occurrence argmax.
                float ma = m[0]; int xa = x[0];
                if (m[1] > ma) { ma = m[1]; xa = x[1]; }
                float mb = m[2]; int xb = x[2];
                if (m[3] > mb) { mb = m[3]; xb = x[3]; }
                if (mb > ma)   { ma = mb;   xa = xb;  }

                const float ns = pc[u] + ma;
                myst = ns;
                ((float*)&stv[rb ^ 1][0])[j] = ns;
                bpout[(size_t)(t - 1) * K_] = (float)xa;
                __syncthreads();
            }
        }
    }

    // Final Viterbi scores.
    *scout = myst;
}

extern "C" void kernel_launch(void* const* d_in, const int* in_sizes, int n_in,
                              void* d_out, int out_size, void* d_ws, size_t ws_size,
                              hipStream_t stream) {
    const float* pot   = (const float*)d_in[0];
    const float* trans = (const float*)d_in[1];
    float* out         = (float*)d_out;
    crf_viterbi_kernel<<<dim3(B_), dim3(K_), 0, stream>>>(pot, trans, out);
}